// Round 4
// baseline (75.249 us; speedup 1.0000x reference)
//
#include <hip/hip_runtime.h>

#define NG   1024
#define NCLS 18
#define HH   100
#define WW   100
#define DD   8
#define PTOT (HH*WW*DD)
#define TI   2      // voxels per block in i
#define TJ   4      // voxels per block in j; k covers all 8  -> 64 voxels = 1 wave
#define CH   64     // survivors derived per chunk (= block size)

// One fused kernel, 1-wave blocks, grid 50x25 = 1250 blocks.
// Per block: ballot-compact cull of 1024 gaussians vs the tile's voxel-center
// AABB (~13 survivors expected), pack survivors' derived data
// {mu, 3s, opa, A = R diag(s^-2) R^T, 17 feats} into float4-friendly LDS rows,
// then each thread (1 voxel) loops survivors with broadcast ds_read_b128.
// Empty gaussian (reference index NG) is closed-form in the epilogue:
// diag cov rng^2=(6400,6400,40.96), mu=(0,0,2.2), feeds only class 17.
__global__ __launch_bounds__(64) void gv_fused(
    const float* __restrict__ means, const float* __restrict__ opac,
    const float* __restrict__ scales, const float* __restrict__ rots,
    const float* __restrict__ feats, const float* __restrict__ es,
    float* __restrict__ out)
{
    __shared__ int s_idx[NG];
    __shared__ __align__(16) float s_g[CH][36];   // 36-float stride: 16B-aligned rows, (4t+c)%32 banks

    const int tid = threadIdx.x;                  // == lane
    const int i0  = blockIdx.x * TI;
    const int j0  = blockIdx.y * TJ;

    // AABB of this tile's voxel CENTERS
    const float xlo = (i0 + 0.5f) * 0.8f - 40.f;
    const float xhi = (i0 + TI - 0.5f) * 0.8f - 40.f;
    const float ylo = (j0 + 0.5f) * 0.8f - 40.f;
    const float yhi = (j0 + TJ - 0.5f) * 0.8f - 40.f;
    const float zlo = -0.6f, zhi = 5.0f;

    // ---- Phase 1: cull via ballot compaction (no atomics) ----
    int ns = 0;
    #pragma unroll 4
    for (int it = 0; it < NG / 64; ++it) {
        int n = it * 64 + tid;
        float mx = means[n*3+0], my = means[n*3+1], mz = means[n*3+2];
        float rx = 3.f*scales[n*3+0], ry = 3.f*scales[n*3+1], rz = 3.f*scales[n*3+2];
        bool ov = (mx - rx <= xhi) & (mx + rx >= xlo)
                & (my - ry <= yhi) & (my + ry >= ylo)
                & (mz - rz <= zhi) & (mz + rz >= zlo);
        unsigned long long m = __ballot(ov);
        if (ov) {
            int pos = __popcll(m & ((1ull << tid) - 1ull));
            s_idx[ns + pos] = n;
        }
        ns += (int)__popcll(m);
    }
    __syncthreads();

    // this thread's voxel
    const int k = tid & 7, dj = (tid >> 3) & 3, di = tid >> 5;
    const int i = i0 + di, j = j0 + dj;
    const float x = (i + 0.5f) * 0.8f - 40.f;
    const float y = (j + 0.5f) * 0.8f - 40.f;
    const float z = (k + 0.5f) * 0.8f - 1.f;

    float acc[17];
    #pragma unroll
    for (int c = 0; c < 17; ++c) acc[c] = 0.f;

    // ---- Phase 2: chunked derived compute + accumulate ----
    for (int base = 0; base < ns; base += CH) {
        const int m = min(CH, ns - base);
        __syncthreads();                          // protect s_g reuse (1-wave: cheap)
        if (tid < m) {
            int n = s_idx[base + tid];
            float qw = rots[n*4+0], qx = rots[n*4+1], qy = rots[n*4+2], qz = rots[n*4+3];
            float inv = rsqrtf(qw*qw + qx*qx + qy*qy + qz*qz);
            qw *= inv; qx *= inv; qy *= inv; qz *= inv;
            float R00 = 1.f - 2.f*(qy*qy + qz*qz), R01 = 2.f*(qx*qy - qw*qz), R02 = 2.f*(qx*qz + qw*qy);
            float R10 = 2.f*(qx*qy + qw*qz), R11 = 1.f - 2.f*(qx*qx + qz*qz), R12 = 2.f*(qy*qz - qw*qx);
            float R20 = 2.f*(qx*qz - qw*qy), R21 = 2.f*(qy*qz + qw*qx), R22 = 1.f - 2.f*(qx*qx + qy*qy);
            float sx = scales[n*3+0], sy = scales[n*3+1], sz = scales[n*3+2];
            float ix = 1.f/(sx*sx), iy = 1.f/(sy*sy), iz = 1.f/(sz*sz);
            float* g = s_g[tid];
            // row layout (float4 q): q0={mux,muy,muz,rx} q1={ry,rz,opa,A00}
            // q2={A01,A02,A11,A12} q3={A22,f0,f1,f2} q4..q7={f3..f16,pad,pad}
            g[0] = means[n*3+0]; g[1] = means[n*3+1]; g[2] = means[n*3+2]; g[3] = 3.f*sx;
            g[4] = 3.f*sy; g[5] = 3.f*sz; g[6] = opac[n];
            g[7]  = R00*R00*ix + R01*R01*iy + R02*R02*iz;   // A00
            g[8]  = R00*R10*ix + R01*R11*iy + R02*R12*iz;   // A01
            g[9]  = R00*R20*ix + R01*R21*iy + R02*R22*iz;   // A02
            g[10] = R10*R10*ix + R11*R11*iy + R12*R12*iz;   // A11
            g[11] = R10*R20*ix + R11*R21*iy + R12*R22*iz;   // A12
            g[12] = R20*R20*ix + R21*R21*iy + R22*R22*iz;   // A22
            #pragma unroll
            for (int c = 0; c < 17; ++c) g[13 + c] = feats[n*17 + c];
            g[30] = 0.f; g[31] = 0.f;
        }
        __syncthreads();

        for (int t = 0; t < m; ++t) {
            const float4* gq = (const float4*)s_g[t];     // wave-uniform -> broadcast
            float4 q0 = gq[0], q1 = gq[1];
            float dx = x - q0.x, dy = y - q0.y, dz = z - q0.z;
            if (fabsf(dx) <= q0.w && fabsf(dy) <= q1.x && fabsf(dz) <= q1.y) {
                float4 q2 = gq[2], q3 = gq[3];
                float maha = dx*(dx*q1.w + 2.f*(dy*q2.x + dz*q2.y))
                           + dy*(dy*q2.z + 2.f*dz*q2.w)
                           + dz*dz*q3.x;
                float w = q1.z * __expf(-0.5f * maha);
                float4 q4 = gq[4], q5 = gq[5], q6 = gq[6], q7 = gq[7];
                acc[0]  = fmaf(w, q3.y, acc[0]);  acc[1]  = fmaf(w, q3.z, acc[1]);
                acc[2]  = fmaf(w, q3.w, acc[2]);
                acc[3]  = fmaf(w, q4.x, acc[3]);  acc[4]  = fmaf(w, q4.y, acc[4]);
                acc[5]  = fmaf(w, q4.z, acc[5]);  acc[6]  = fmaf(w, q4.w, acc[6]);
                acc[7]  = fmaf(w, q5.x, acc[7]);  acc[8]  = fmaf(w, q5.y, acc[8]);
                acc[9]  = fmaf(w, q5.z, acc[9]);  acc[10] = fmaf(w, q5.w, acc[10]);
                acc[11] = fmaf(w, q6.x, acc[11]); acc[12] = fmaf(w, q6.y, acc[12]);
                acc[13] = fmaf(w, q6.z, acc[13]); acc[14] = fmaf(w, q6.w, acc[14]);
                acc[15] = fmaf(w, q7.x, acc[15]); acc[16] = fmaf(w, q7.y, acc[16]);
            }
        }
    }

    // ---- Epilogue: closed-form empty gaussian + stores ----
    const int p = (i * WW + j) * DD + k;
    float dz0 = z - 2.2f;
    float me  = x*x*(1.f/6400.f) + y*y*(1.f/6400.f) + dz0*dz0*(1.f/40.96f);
    float w17 = es[0] * __expf(-0.5f * me);
    out[p] = 0.f;                                 // grid_density
    float* o = out + PTOT + p * NCLS;
    #pragma unroll
    for (int c = 0; c < 17; ++c) o[c] = acc[c];
    o[17] = w17;
}

extern "C" void kernel_launch(void* const* d_in, const int* in_sizes, int n_in,
                              void* d_out, int out_size, void* d_ws, size_t ws_size,
                              hipStream_t stream) {
    const float* means  = (const float*)d_in[0];
    const float* opac   = (const float*)d_in[1];
    const float* scales = (const float*)d_in[2];
    const float* rots   = (const float*)d_in[3];
    const float* feats  = (const float*)d_in[4];
    const float* es     = (const float*)d_in[5];
    float* out = (float*)d_out;

    dim3 grid(HH / TI, WW / TJ);                  // 50 x 25 = 1250 one-wave blocks
    gv_fused<<<grid, 64, 0, stream>>>(means, opac, scales, rots, feats, es, out);
}